// Round 4
// baseline (99.846 us; speedup 1.0000x reference)
//
#include <hip/hip_runtime.h>
#include <math.h>

#define B_ 64
#define L_ 512
#define N_ 321
#define P_ 720
#define E_ 8
#define R_ 32
#define CID_ 32
#define H_ 64
#define ER_ 256
#define KB2 288   // ER_ + 8 bias-rank + 1 mean + 23 zero-pad (9 K-steps of 32)

typedef __attribute__((ext_vector_type(8))) short bf16x8;
typedef __attribute__((ext_vector_type(4))) float f32x4;
typedef __attribute__((ext_vector_type(8))) unsigned short u16x8;
typedef __attribute__((ext_vector_type(4))) unsigned short u16x4;
typedef __attribute__((ext_vector_type(2))) unsigned short u16x2;

// workspace layout (float offsets)
#define OFF_GATE 0                       // N*E = 2568
#define OFF_CS1  (N_*E_)                 // 2568, 256 floats
#define OFF_W1K  (OFF_CS1 + ER_)         // 2824 (bf16 256*512 = 65536 floats)
#define OFF_W2X  (OFF_W1K + ER_*L_/2)    // 68360 (bf16 720*288 = 103680 floats)
// total ≈ 172K floats ≈ 688 KB

__device__ __forceinline__ unsigned short f2bf(float f) {
    unsigned u = __float_as_uint(f);
    u += 0x7fffu + ((u >> 16) & 1u);
    return (unsigned short)(u >> 16);
}
__device__ __forceinline__ float bf2f(unsigned short h) {
    return __uint_as_float(((unsigned)h) << 16);
}

// ---------------- router ----------------------------------------------------
__global__ void router_kernel(const float* __restrict__ ident,
                              const float* __restrict__ rw1, const float* __restrict__ rb1,
                              const float* __restrict__ rw2, const float* __restrict__ rb2,
                              float* __restrict__ gate) {
    int n = blockIdx.x;
    int t = threadIdx.x;  // 0..63
    __shared__ float hid[H_];
    __shared__ float lg[E_];
    float acc = rb1[t];
    #pragma unroll
    for (int c = 0; c < CID_; ++c)
        acc = fmaf(ident[n*CID_ + c], rw1[c*H_ + t], acc);
    hid[t] = fmaxf(acc, 0.f);
    __syncthreads();
    if (t < E_) {
        float a = rb2[t];
        #pragma unroll
        for (int h = 0; h < H_; ++h) a = fmaf(hid[h], rw2[h*E_ + t], a);
        lg[t] = a;
    }
    __syncthreads();
    if (t == 0) {
        float m = lg[0];
        #pragma unroll
        for (int e = 1; e < E_; ++e) m = fmaxf(m, lg[e]);
        float s = 0.f, ex[E_];
        #pragma unroll
        for (int e = 0; e < E_; ++e) { ex[e] = expf(lg[e] - m); s += ex[e]; }
        float inv = 1.f / s;
        #pragma unroll
        for (int e = 0; e < E_; ++e) gate[n*E_ + e] = ex[e] * inv;
    }
}

// ---------------- prep: w1k [er][l], w2x [p][288], cs1 ----------------------
__global__ void prep_kernel(const float* __restrict__ w1, const float* __restrict__ w2,
                            const float* __restrict__ bias,
                            unsigned short* __restrict__ w1k, unsigned short* __restrict__ w2x,
                            float* __restrict__ cs1) {
    __shared__ float red[16][32];
    int bid = blockIdx.x, t = threadIdx.x;
    if (bid < 256) {                  // w1k [er][l]: 256*512 elems, 512 thr/block
        int g = bid*512 + t;
        int er = g >> 9, l = g & 511;
        w1k[g] = f2bf(w1[(size_t)(er >> 5)*(L_*R_) + (size_t)l*R_ + (er & 31)]);
    } else if (bid < 256 + 720) {     // w2x row p: K-extended
        int p = bid - 256;
        if (t < KB2) {
            unsigned short v;
            if (t < ER_)            v = f2bf(w2[(size_t)t*P_ + p]);
            else if (t < ER_ + E_)  v = f2bf(bias[(size_t)(t - ER_)*P_ + p]);
            else if (t == ER_ + E_) v = 0x3f80;  // bf16(1.0) for the mean lane
            else                    v = 0;
            w2x[(size_t)p*KB2 + t] = v;
        }
    } else {                          // cs1: 8 blocks, one expert each
        int e = bid - 976;
        int q = t >> 5, r = t & 31;
        float s = 0.f;
        for (int l = q; l < L_; l += 16)
            s += bf2f(f2bf(w1[(size_t)e*(L_*R_) + (size_t)l*R_ + r]));
        red[q][r] = s;
        __syncthreads();
        if (q == 0) {
            #pragma unroll
            for (int qq = 1; qq < 16; ++qq) s += red[qq][r];
            cs1[e*32 + r] = s;
        }
    }
}

// ---------------- fused kernel ----------------------------------------------
// Per (b, 32-n-tile):
//  Stage A: hg[n][er] = gate[n,e]*(sum_l w1k[er,l]*x[b,l,n] - mean*cs1[er])  (LDS)
//           + K-extension rows: hg[n][256+e]=gate*sd, hg[n][264]=mean
//  Stage B: out[b,p,n] = sum_k w2x[p,k]*hg[n,k]   (K=288, barrier-free)
#define HG_STRIDE 296   // u16; 148 dwords -> 2-way bank aliasing only
#define SM_AS   0                       // u16 [2][256][40] = 40960 B
#define SM_BS   40960                   // u16 [2][32][40]  = 5120 B
#define SM_RED  (40960+5120)            // f32 [2][16][32]  = 4096 B
#define SM_MS   (SM_RED+4096)           // f32 [32]
#define SM_SD   (SM_MS+128)             // f32 [32]
#define SM_TOT  (SM_SD+128)             // 50432 B ; hgtile u16[32][296]=18944 overlaps SM_AS

__global__ __launch_bounds__(512, 6) void fused_kernel(
        const float* __restrict__ x, const unsigned short* __restrict__ w1k,
        const unsigned short* __restrict__ w2x, const float* __restrict__ gate,
        const float* __restrict__ cs1, float* __restrict__ out) {
    __shared__ __align__(16) char smem[SM_TOT];
    unsigned short* As  = (unsigned short*)(smem + SM_AS);   // [2][256][40]
    unsigned short* Bs  = (unsigned short*)(smem + SM_BS);   // [2][32][40]
    float* red1 = (float*)(smem + SM_RED);                   // [16][32]
    float* red2 = red1 + 512;
    float* meanS = (float*)(smem + SM_MS);
    float* sdS   = (float*)(smem + SM_SD);
    unsigned short* hgt = (unsigned short*)(smem + SM_AS);   // [32][296] (union)

    const int n0 = blockIdx.x * 32;
    const int b  = blockIdx.y;
    const int tid = threadIdx.x;
    const int lane = tid & 63;
    const int wave = tid >> 6;          // 0..7  (== expert id in stage A)
    const int l15 = lane & 15;
    const int kgrp = lane >> 4;         // 0..3

    // ---- stage A ----
    const int arow = tid >> 1;          // 0..255
    const int acol = (tid & 1) * 16;
    const int xn  = tid & 31;
    const int xk2 = (tid >> 5) * 2;     // 0..30
    const float* xb = x + (size_t)b * L_ * N_;
    const int gn = n0 + xn;
    const bool nvalid = (gn < N_);

    float s1 = 0.f, s2 = 0.f;
    u16x8 a0, a1;
    float xv0, xv1;

    f32x4 acc[2][2];
    #pragma unroll
    for (int i = 0; i < 2; ++i)
        #pragma unroll
        for (int j = 0; j < 2; ++j) acc[i][j] = (f32x4){0.f,0.f,0.f,0.f};

    // prologue tile 0
    a0 = *(const u16x8*)&w1k[(size_t)arow*L_ + acol];
    a1 = *(const u16x8*)&w1k[(size_t)arow*L_ + acol + 8];
    xv0 = nvalid ? xb[(size_t)xk2*N_ + gn] : 0.f;
    xv1 = nvalid ? xb[(size_t)(xk2+1)*N_ + gn] : 0.f;
    *(u16x8*)&As[(size_t)arow*40 + acol]     = a0;
    *(u16x8*)&As[(size_t)arow*40 + acol + 8] = a1;
    {
        s1 += xv0 + xv1; s2 = fmaf(xv0, xv0, s2); s2 = fmaf(xv1, xv1, s2);
        u16x2 bp; bp[0] = f2bf(xv0); bp[1] = f2bf(xv1);
        *(u16x2*)&Bs[(size_t)xn*40 + xk2] = bp;
    }
    __syncthreads();

    for (int t = 0; t < 16; ++t) {
        const int cur = t & 1;
        if (t < 15) {
            int k0 = (t + 1) * 32;
            a0 = *(const u16x8*)&w1k[(size_t)arow*L_ + k0 + acol];
            a1 = *(const u16x8*)&w1k[(size_t)arow*L_ + k0 + acol + 8];
            xv0 = nvalid ? xb[(size_t)(k0 + xk2)*N_ + gn] : 0.f;
            xv1 = nvalid ? xb[(size_t)(k0 + xk2 + 1)*N_ + gn] : 0.f;
        }
        bf16x8 af[2], bfv[2];
        #pragma unroll
        for (int fm = 0; fm < 2; ++fm)
            af[fm] = *(const bf16x8*)&As[(size_t)(cur*256 + wave*32 + fm*16 + l15)*40 + kgrp*8];
        #pragma unroll
        for (int fn = 0; fn < 2; ++fn)
            bfv[fn] = *(const bf16x8*)&Bs[(size_t)(cur*32 + fn*16 + l15)*40 + kgrp*8];
        #pragma unroll
        for (int fm = 0; fm < 2; ++fm)
            #pragma unroll
            for (int fn = 0; fn < 2; ++fn)
                acc[fm][fn] = __builtin_amdgcn_mfma_f32_16x16x32_bf16(af[fm], bfv[fn], acc[fm][fn], 0, 0, 0);
        if (t < 15) {
            const int nxt = cur ^ 1;
            *(u16x8*)&As[(size_t)(nxt*256 + arow)*40 + acol]     = a0;
            *(u16x8*)&As[(size_t)(nxt*256 + arow)*40 + acol + 8] = a1;
            s1 += xv0 + xv1; s2 = fmaf(xv0, xv0, s2); s2 = fmaf(xv1, xv1, s2);
            u16x2 bp; bp[0] = f2bf(xv0); bp[1] = f2bf(xv1);
            *(u16x2*)&Bs[(size_t)(nxt*32 + xn)*40 + xk2] = bp;
        }
        __syncthreads();
    }

    // ---- stats ----
    red1[(tid >> 5)*32 + xn] = s1;
    red2[(tid >> 5)*32 + xn] = s2;
    __syncthreads();
    if (tid < 32) {
        float a = 0.f, q = 0.f;
        #pragma unroll
        for (int kk = 0; kk < 16; ++kk) { a += red1[kk*32 + tid]; q += red2[kk*32 + tid]; }
        float mean = a * (1.f/L_);
        float var = (q - (float)L_*mean*mean) * (1.f/(L_-1));
        var = fmaxf(var, 0.f);
        meanS[tid] = mean;
        sdS[tid]   = sqrtf(var) + 1e-6f;
    }
    __syncthreads();

    // ---- stage A epilogue: write hgtile (overlaps As — all As reads done) ----
    #pragma unroll
    for (int fm = 0; fm < 2; ++fm) {
        int er0 = wave*32 + fm*16 + kgrp*4;
        f32x4 c4 = *(const f32x4*)&cs1[er0];
        #pragma unroll
        for (int fn = 0; fn < 2; ++fn) {
            int nl = fn*16 + l15;
            int gnn = n0 + nl; if (gnn > N_-1) gnn = N_-1;
            float g = gate[gnn*E_ + wave];
            float m = meanS[nl];
            u16x4 pk;
            #pragma unroll
            for (int j = 0; j < 4; ++j)
                pk[j] = f2bf(g * (acc[fm][fn][j] - m * c4[j]));
            *(u16x4*)&hgt[(size_t)nl*HG_STRIDE + er0] = pk;
        }
    }
    if (tid < 256) {   // K-extension rows: k 256..287
        int nl = tid >> 3, seg = tid & 7;
        int gnn = n0 + nl; if (gnn > N_-1) gnn = N_-1;
        float sd = sdS[nl], m = meanS[nl];
        u16x4 pk;
        #pragma unroll
        for (int jj = 0; jj < 4; ++jj) {
            int k = seg*4 + jj;             // 0..31 within extension
            float v = (k < E_) ? gate[gnn*E_ + k] * sd : ((k == E_) ? m : 0.f);
            pk[jj] = f2bf(v);
        }
        *(u16x4*)&hgt[(size_t)nl*HG_STRIDE + ER_ + seg*4] = pk;
    }
    __syncthreads();

    // ---- stage B: out[p][n-tile] = w2x[p][0:288] . hgt[n][0:288], barrier-free ----
    const int nA = n0 + l15;
    const int nBv = n0 + 16 + l15;
    for (int pt = wave; pt < P_/16; pt += 8) {
        const unsigned short* ap = w2x + (size_t)(pt*16 + l15)*KB2;
        bf16x8 afr = *(const bf16x8*)&ap[kgrp*8];
        f32x4 o0 = (f32x4){0.f,0.f,0.f,0.f};
        f32x4 o1 = (f32x4){0.f,0.f,0.f,0.f};
        #pragma unroll
        for (int k = 0; k < 9; ++k) {
            bf16x8 an;
            if (k < 8) an = *(const bf16x8*)&ap[(k+1)*32 + kgrp*8];
            bf16x8 b0 = *(const bf16x8*)&hgt[(size_t)l15*HG_STRIDE + k*32 + kgrp*8];
            bf16x8 b1 = *(const bf16x8*)&hgt[(size_t)(16 + l15)*HG_STRIDE + k*32 + kgrp*8];
            o0 = __builtin_amdgcn_mfma_f32_16x16x32_bf16(afr, b0, o0, 0, 0, 0);
            o1 = __builtin_amdgcn_mfma_f32_16x16x32_bf16(afr, b1, o1, 0, 0, 0);
            if (k < 8) afr = an;
        }
        int pbase = pt*16 + kgrp*4;
        #pragma unroll
        for (int j = 0; j < 4; ++j) {
            float* orow = out + ((size_t)b*P_ + pbase + j)*N_;
            if (nA < N_)  orow[nA]  = o0[j];
            if (nBv < N_) orow[nBv] = o1[j];
        }
    }
}

extern "C" void kernel_launch(void* const* d_in, const int* in_sizes, int n_in,
                              void* d_out, int out_size, void* d_ws, size_t ws_size,
                              hipStream_t stream) {
    const float* x     = (const float*)d_in[0];
    const float* ident = (const float*)d_in[1];
    const float* rw1   = (const float*)d_in[2];
    const float* rb1   = (const float*)d_in[3];
    const float* rw2   = (const float*)d_in[4];
    const float* rb2   = (const float*)d_in[5];
    const float* w1    = (const float*)d_in[6];
    const float* w2    = (const float*)d_in[7];
    const float* bias  = (const float*)d_in[8];
    float* out = (float*)d_out;
    float* ws  = (float*)d_ws;

    float* gate = ws + OFF_GATE;
    float* cs1  = ws + OFF_CS1;
    unsigned short* w1k = (unsigned short*)(ws + OFF_W1K);
    unsigned short* w2x = (unsigned short*)(ws + OFF_W2X);

    router_kernel<<<N_, 64, 0, stream>>>(ident, rw1, rb1, rw2, rb2, gate);
    prep_kernel<<<256 + 720 + 8, 512, 0, stream>>>(w1, w2, bias, w1k, w2x, cs1);
    fused_kernel<<<dim3((N_+31)/32, B_), 512, 0, stream>>>(x, w1k, w2x, gate, cs1, out);
}

// Round 5
// 69.832 us; speedup vs baseline: 1.4298x; 1.4298x over previous
//
#include <hip/hip_runtime.h>
#include <math.h>

#define B_ 64
#define L_ 512
#define N_ 321
#define P_ 720
#define E_ 8
#define R_ 32
#define CID_ 32
#define H_ 64
#define ER_ 256
#define KB2 288   // ER_ + 8 bias-rank + 1 mean + 23 zero-pad (9 K-steps of 32)

typedef __attribute__((ext_vector_type(8))) short bf16x8;
typedef __attribute__((ext_vector_type(4))) float f32x4;
typedef __attribute__((ext_vector_type(8))) unsigned short u16x8;
typedef __attribute__((ext_vector_type(4))) unsigned short u16x4;

// workspace layout (float offsets)
#define OFF_GATE 0                       // N*E = 2568
#define OFF_CS1  (N_*E_)                 // 256 floats
#define OFF_W1K  (OFF_CS1 + ER_)         // bf16 256*512
#define OFF_W2X  (OFF_W1K + ER_*L_/2)    // bf16 720*288

__device__ __forceinline__ unsigned short f2bf(float f) {
    unsigned u = __float_as_uint(f);
    u += 0x7fffu + ((u >> 16) & 1u);
    return (unsigned short)(u >> 16);
}
__device__ __forceinline__ float bf2f(unsigned short h) {
    return __uint_as_float(((unsigned)h) << 16);
}

// ---------------- router ----------------------------------------------------
__global__ void router_kernel(const float* __restrict__ ident,
                              const float* __restrict__ rw1, const float* __restrict__ rb1,
                              const float* __restrict__ rw2, const float* __restrict__ rb2,
                              float* __restrict__ gate) {
    int n = blockIdx.x;
    int t = threadIdx.x;  // 0..63
    __shared__ float hid[H_];
    __shared__ float lg[E_];
    float acc = rb1[t];
    #pragma unroll
    for (int c = 0; c < CID_; ++c)
        acc = fmaf(ident[n*CID_ + c], rw1[c*H_ + t], acc);
    hid[t] = fmaxf(acc, 0.f);
    __syncthreads();
    if (t < E_) {
        float a = rb2[t];
        #pragma unroll
        for (int h = 0; h < H_; ++h) a = fmaf(hid[h], rw2[h*E_ + t], a);
        lg[t] = a;
    }
    __syncthreads();
    if (t == 0) {
        float m = lg[0];
        #pragma unroll
        for (int e = 1; e < E_; ++e) m = fmaxf(m, lg[e]);
        float s = 0.f, ex[E_];
        #pragma unroll
        for (int e = 0; e < E_; ++e) { ex[e] = expf(lg[e] - m); s += ex[e]; }
        float inv = 1.f / s;
        #pragma unroll
        for (int e = 0; e < E_; ++e) gate[n*E_ + e] = ex[e] * inv;
    }
}

// ---------------- prep: w1k [er][l], w2x [p][288], cs1 ----------------------
__global__ void prep_kernel(const float* __restrict__ w1, const float* __restrict__ w2,
                            const float* __restrict__ bias,
                            unsigned short* __restrict__ w1k, unsigned short* __restrict__ w2x,
                            float* __restrict__ cs1) {
    __shared__ float red[16][32];
    int bid = blockIdx.x, t = threadIdx.x;
    if (bid < 256) {                  // w1k [er][l]: 256*512 elems
        int g = bid*512 + t;
        int er = g >> 9, l = g & 511;
        w1k[g] = f2bf(w1[(size_t)(er >> 5)*(L_*R_) + (size_t)l*R_ + (er & 31)]);
    } else if (bid < 256 + 720) {     // w2x row p: K-extended
        int p = bid - 256;
        if (t < KB2) {
            unsigned short v;
            if (t < ER_)            v = f2bf(w2[(size_t)t*P_ + p]);
            else if (t < ER_ + E_)  v = f2bf(bias[(size_t)(t - ER_)*P_ + p]);
            else if (t == ER_ + E_) v = 0x3f80;  // bf16(1.0) for the mean lane
            else                    v = 0;
            w2x[(size_t)p*KB2 + t] = v;
        }
    } else {                          // cs1: 8 blocks, one expert each
        int e = bid - 976;
        int q = t >> 5, r = t & 31;
        float s = 0.f;
        for (int l = q; l < L_; l += 16)
            s += bf2f(f2bf(w1[(size_t)e*(L_*R_) + (size_t)l*R_ + r]));
        red[q][r] = s;
        __syncthreads();
        if (q == 0) {
            #pragma unroll
            for (int qq = 1; qq < 16; ++qq) s += red[qq][r];
            cs1[e*32 + r] = s;
        }
    }
}

// ---------------- fused kernel ----------------------------------------------
// Per (b, 64-n-tile):
//  Stage A (BM=256er, BN=64n, BK=32, 16 steps, x reg-ring depth 3):
//      hgt[n][er] = gate[n,e]*(sum_l w1k[er,l]*x[b,l,n] - mean*cs1[er])  (LDS)
//      + K-ext: hgt[n][256+e]=gate*sd, hgt[n][264]=mean
//  Stage B: out[b,p,n-tile] = w2x[p,0:288] . hgt[n,0:288], per-wave 32p x 64n
//      tiles, stores via LDS patch -> 256B-contiguous float4 rows.
#define HG_STRIDE 296   // u16
#define SM_AS   0               // u16 [2][256][40] = 40960 B (union hgt [64][296] = 37888)
#define SM_BS   40960           // u16 [2][64][40]  = 10240 B
#define SM_RED  51200           // f32 [2][8][64]   = 4096 B
#define SM_MSD  55296           // f32 [2][64]      = 512 B
#define SM_OUT  40960           // f32 [8][16][68]  = 34816 B (union Bs/red/msd)
#define SM_TOT  75776

__global__ __launch_bounds__(512, 4) void fused_kernel(
        const float* __restrict__ x, const unsigned short* __restrict__ w1k,
        const unsigned short* __restrict__ w2x, const float* __restrict__ gate,
        const float* __restrict__ cs1, float* __restrict__ out) {
    __shared__ __align__(16) char smem[SM_TOT];
    unsigned short* As  = (unsigned short*)(smem + SM_AS);   // [2][256][40]
    unsigned short* Bs  = (unsigned short*)(smem + SM_BS);   // [2][64][40]
    float* red1 = (float*)(smem + SM_RED);                   // [8][64]
    float* red2 = red1 + 512;
    float* meanS = (float*)(smem + SM_MSD);
    float* sdS   = meanS + 64;
    unsigned short* hgt = (unsigned short*)(smem + SM_AS);   // [64][296] (union)

    const int n0 = blockIdx.x * 64;
    const int b  = blockIdx.y;
    const int tid = threadIdx.x;
    const int lane = tid & 63;
    const int wave = tid >> 6;          // 0..7
    const int wm = wave >> 1;           // er-base = wm*64
    const int wn = wave & 1;            // n-base = wn*32
    const int l15 = lane & 15;
    const int kgrp = lane >> 4;         // 0..3

    // ---- stage A ----
    const int arow = tid >> 1;          // 0..255
    const int acol = (tid & 1) * 16;    // 0/16
    const int xn  = tid & 63;
    const int xkb = wave * 4;           // 0..28
    const float* xb = x + (size_t)b * L_ * N_;
    const int gn = n0 + xn;
    const bool nvalid = (gn < N_);

    float s1 = 0.f, s2 = 0.f;
    float xr[3][4];
    u16x8 ar[2][2];

    f32x4 acc[4][2];
    #pragma unroll
    for (int i = 0; i < 4; ++i)
        #pragma unroll
        for (int j = 0; j < 2; ++j) acc[i][j] = (f32x4){0.f,0.f,0.f,0.f};

#define LOADX(s_, t_) { const int k0 = (t_)*32;                                  \
    _Pragma("unroll")                                                            \
    for (int i_ = 0; i_ < 4; ++i_)                                               \
        xr[s_][i_] = nvalid ? xb[(size_t)(k0 + xkb + i_)*N_ + gn] : 0.f; }
#define LOADA(s_, t_) { const int k0 = (t_)*32;                                  \
    ar[s_][0] = *(const u16x8*)&w1k[(size_t)arow*L_ + k0 + acol];                \
    ar[s_][1] = *(const u16x8*)&w1k[(size_t)arow*L_ + k0 + acol + 8]; }
#define STAGE(nb_, xs_, as_) {                                                   \
    *(u16x8*)&As[(size_t)((nb_)*256 + arow)*40 + acol]     = ar[as_][0];         \
    *(u16x8*)&As[(size_t)((nb_)*256 + arow)*40 + acol + 8] = ar[as_][1];         \
    u16x4 bp_;                                                                   \
    _Pragma("unroll")                                                            \
    for (int i_ = 0; i_ < 4; ++i_) {                                             \
        float v_ = xr[xs_][i_]; s1 += v_; s2 = fmaf(v_, v_, s2);                 \
        bp_[i_] = f2bf(v_); }                                                    \
    *(u16x4*)&Bs[(size_t)((nb_)*64 + xn)*40 + xkb] = bp_; }

    LOADX(0, 0); LOADA(0, 0);
    LOADX(1, 1); LOADA(1, 1);
    LOADX(2, 2);
    STAGE(0, 0, 0);
    __syncthreads();

    #pragma unroll
    for (int t = 0; t < 16; ++t) {
        if (t + 3 < 16) LOADX((t + 3) % 3, t + 3);
        if (t + 2 < 16) LOADA((t + 2) & 1, t + 2);
        const int cur = t & 1;
        bf16x8 af[4], bfv[2];
        #pragma unroll
        for (int fm = 0; fm < 4; ++fm)
            af[fm] = *(const bf16x8*)&As[(size_t)(cur*256 + wm*64 + fm*16 + l15)*40 + kgrp*8];
        #pragma unroll
        for (int fn = 0; fn < 2; ++fn)
            bfv[fn] = *(const bf16x8*)&Bs[(size_t)(cur*64 + wn*32 + fn*16 + l15)*40 + kgrp*8];
        #pragma unroll
        for (int fm = 0; fm < 4; ++fm)
            #pragma unroll
            for (int fn = 0; fn < 2; ++fn)
                acc[fm][fn] = __builtin_amdgcn_mfma_f32_16x16x32_bf16(af[fm], bfv[fn], acc[fm][fn], 0, 0, 0);
        if (t < 15) STAGE((t + 1) & 1, (t + 1) % 3, (t + 1) & 1);
        __syncthreads();
    }

    // ---- stats ----
    red1[wave*64 + xn] = s1;
    red2[wave*64 + xn] = s2;
    __syncthreads();
    if (tid < 64) {
        float a = 0.f, q = 0.f;
        #pragma unroll
        for (int kk = 0; kk < 8; ++kk) { a += red1[kk*64 + tid]; q += red2[kk*64 + tid]; }
        float mean = a * (1.f/L_);
        float var = (q - (float)L_*mean*mean) * (1.f/(L_-1));
        var = fmaxf(var, 0.f);
        meanS[tid] = mean;
        sdS[tid]   = sqrtf(var) + 1e-6f;
    }
    __syncthreads();

    // ---- stage A epilogue: write hgt (unions As; all As reads done) ----
    #pragma unroll
    for (int fm = 0; fm < 4; ++fm) {
        int er0 = wm*64 + fm*16 + kgrp*4;
        int e = er0 >> 5;
        f32x4 c4 = *(const f32x4*)&cs1[er0];
        #pragma unroll
        for (int fn = 0; fn < 2; ++fn) {
            int nl = wn*32 + fn*16 + l15;
            int gnn = n0 + nl; if (gnn > N_-1) gnn = N_-1;
            float g = gate[gnn*E_ + e];
            float m = meanS[nl];
            u16x4 pk;
            #pragma unroll
            for (int j = 0; j < 4; ++j)
                pk[j] = f2bf(g * (acc[fm][fn][j] - m * c4[j]));
            *(u16x4*)&hgt[(size_t)nl*HG_STRIDE + er0] = pk;
        }
    }
    {   // K-extension cols 256..287 for all 64 rows
        int nl = tid >> 3, seg = tid & 7;
        int gnn = n0 + nl; if (gnn > N_-1) gnn = N_-1;
        float sd = sdS[nl], m = meanS[nl];
        u16x4 pk;
        #pragma unroll
        for (int jj = 0; jj < 4; ++jj) {
            int k = seg*4 + jj;
            float v = (k < E_) ? gate[gnn*E_ + k] * sd : ((k == E_) ? m : 0.f);
            pk[jj] = f2bf(v);
        }
        *(u16x4*)&hgt[(size_t)nl*HG_STRIDE + ER_ + seg*4] = pk;
    }
    __syncthreads();

    // ---- stage B: per-wave 32p x 64n tiles, K=288, barrier-free ----
    float* patch = (float*)(smem + SM_OUT) + wave * 1088;   // [16][68] f32
    for (int pt = wave; pt < 23; pt += 8) {
        const int p0w = pt * 32;
        int pr0 = p0w + l15;       if (pr0 > P_-1) pr0 = P_-1;
        int pr1 = p0w + 16 + l15;  if (pr1 > P_-1) pr1 = P_-1;
        const unsigned short* ap0 = w2x + (size_t)pr0*KB2;
        const unsigned short* ap1 = w2x + (size_t)pr1*KB2;

        f32x4 o[2][4];
        #pragma unroll
        for (int i = 0; i < 2; ++i)
            #pragma unroll
            for (int j = 0; j < 4; ++j) o[i][j] = (f32x4){0.f,0.f,0.f,0.f};

        #pragma unroll
        for (int ks = 0; ks < 9; ++ks) {
            bf16x8 a0f = *(const bf16x8*)&ap0[ks*32 + kgrp*8];
            bf16x8 a1f = *(const bf16x8*)&ap1[ks*32 + kgrp*8];
            bf16x8 bfr[4];
            #pragma unroll
            for (int fn = 0; fn < 4; ++fn)
                bfr[fn] = *(const bf16x8*)&hgt[(size_t)(fn*16 + l15)*HG_STRIDE + ks*32 + kgrp*8];
            #pragma unroll
            for (int fn = 0; fn < 4; ++fn) {
                o[0][fn] = __builtin_amdgcn_mfma_f32_16x16x32_bf16(a0f, bfr[fn], o[0][fn], 0, 0, 0);
                o[1][fn] = __builtin_amdgcn_mfma_f32_16x16x32_bf16(a1f, bfr[fn], o[1][fn], 0, 0, 0);
            }
        }

        // epilogue: LDS transpose patch -> 256B-contiguous float4 stores
        #pragma unroll
        for (int fp = 0; fp < 2; ++fp) {
            #pragma unroll
            for (int fn = 0; fn < 4; ++fn)
                #pragma unroll
                for (int j = 0; j < 4; ++j)
                    patch[(kgrp*4 + j)*68 + fn*16 + l15] = o[fp][fn][j];
            __builtin_amdgcn_s_waitcnt(0);   // lgkmcnt(0): own-wave LDS writes visible
            #pragma unroll
            for (int s = 0; s < 4; ++s) {
                int prow = p0w + fp*16 + 4*s + kgrp;
                f32x4 v = *(const f32x4*)&patch[(4*s + kgrp)*68 + l15*4];
                int nn = n0 + l15*4;
                if (prow < P_) {
                    float* orow = out + ((size_t)b*P_ + prow)*N_;
                    if (nn + 3 < N_) {
                        *(f32x4*)&orow[nn] = v;
                    } else {
                        #pragma unroll
                        for (int q = 0; q < 4; ++q)
                            if (nn + q < N_) orow[nn + q] = v[q];
                    }
                }
            }
        }
    }
#undef LOADX
#undef LOADA
#undef STAGE
}

extern "C" void kernel_launch(void* const* d_in, const int* in_sizes, int n_in,
                              void* d_out, int out_size, void* d_ws, size_t ws_size,
                              hipStream_t stream) {
    const float* x     = (const float*)d_in[0];
    const float* ident = (const float*)d_in[1];
    const float* rw1   = (const float*)d_in[2];
    const float* rb1   = (const float*)d_in[3];
    const float* rw2   = (const float*)d_in[4];
    const float* rb2   = (const float*)d_in[5];
    const float* w1    = (const float*)d_in[6];
    const float* w2    = (const float*)d_in[7];
    const float* bias  = (const float*)d_in[8];
    float* out = (float*)d_out;
    float* ws  = (float*)d_ws;

    float* gate = ws + OFF_GATE;
    float* cs1  = ws + OFF_CS1;
    unsigned short* w1k = (unsigned short*)(ws + OFF_W1K);
    unsigned short* w2x = (unsigned short*)(ws + OFF_W2X);

    router_kernel<<<N_, 64, 0, stream>>>(ident, rw1, rb1, rw2, rb2, gate);
    prep_kernel<<<256 + 720 + 8, 512, 0, stream>>>(w1, w2, bias, w1k, w2x, cs1);
    fused_kernel<<<dim3((N_+63)/64, B_), 512, 0, stream>>>(x, w1k, w2x, gate, cs1, out);
}